// Round 11
// baseline (311.791 us; speedup 1.0000x reference)
//
#include <hip/hip_runtime.h>
#include <math.h>

typedef int      v2i __attribute__((ext_vector_type(2)));
typedef int      v4i __attribute__((ext_vector_type(4)));
typedef float    v2f __attribute__((ext_vector_type(2)));
typedef float    v4f __attribute__((ext_vector_type(4)));
typedef _Float16 v4h __attribute__((ext_vector_type(4)));

// Packed marching-tets rows: entry j = (tri_table[idx][j]+1) << (3*j)  (3 bits,
// 0 means "-1 / unused"), plus num_tri << 18. Generated from TRI_TABLE.
__constant__ int c_tri_pack[16] = {
    0,      262346, 262413, 705770, 262548, 681571, 713834, 262557,
    262389, 617045, 649308, 262562, 608981, 262476, 262283, 0};

// ---- pack {pos.xyz, sdf} into half4 (8 B) per vertex (into d_ws) ----
// Gather working set: 600K * 8B = 4.8 MB -> ~L2-resident per XCD.
__global__ void __launch_bounds__(256) pack_kernel(
        const float* __restrict__ pos, const float* __restrict__ sdf,
        v4h* __restrict__ packed, int N) {
    int t = blockIdx.x * blockDim.x + threadIdx.x;
    int v0 = 4 * t;
    if (v0 >= N) return;

    // fp16 sign-preserving sdf: tiny positive must stay positive so the
    // crossing mask matches the f32 sign test used in the tets phase.
    auto h_sdf = [](float s) -> _Float16 {
        _Float16 h = (_Float16)s;
        if (s > 0.0f && !(h > (_Float16)0)) h = (_Float16)6.0e-8f;
        return h;
    };

    if (v0 + 4 <= N) {
        const v4f* pos4 = (const v4f*)pos;
        v4f p0 = pos4[3LL * t], p1 = pos4[3LL * t + 1], p2 = pos4[3LL * t + 2];
        v4f s  = ((const v4f*)sdf)[t];
        v4h h0 = {(_Float16)p0.x, (_Float16)p0.y, (_Float16)p0.z, h_sdf(s.x)};
        v4h h1 = {(_Float16)p0.w, (_Float16)p1.x, (_Float16)p1.y, h_sdf(s.y)};
        v4h h2 = {(_Float16)p1.z, (_Float16)p1.w, (_Float16)p2.x, h_sdf(s.z)};
        v4h h3 = {(_Float16)p2.y, (_Float16)p2.z, (_Float16)p2.w, h_sdf(s.w)};
        // combine pairs into 16B stores
        v4f o01, o23;
        ((v4h*)&o01)[0] = h0; ((v4h*)&o01)[1] = h1;
        ((v4h*)&o23)[0] = h2; ((v4h*)&o23)[1] = h3;
        v4f* dst = (v4f*)(packed + v0);
        dst[0] = o01; dst[1] = o23;
    } else {
        for (int v = v0; v < N; ++v) {
            v4h o = {(_Float16)pos[3LL * v], (_Float16)pos[3LL * v + 1],
                     (_Float16)pos[3LL * v + 2], h_sdf(sdf[v])};
            packed[v] = o;
        }
    }
}

__device__ __forceinline__ void interp_edge(v4h P0, v4h P1,
                                            float& ox, float& oy, float& oz) {
    float s0 = (float)P0.w, s1 = (float)P1.w;
    bool c = (s0 > 0.0f) != (s1 > 0.0f);
    float d = c ? (s0 - s1) : 1.0f;
    float w0 = -s1 / d, w1 = s0 / d;
    ox = c ? ((float)P0.x * w0 + (float)P1.x * w1) : 0.0f;
    oy = c ? ((float)P0.y * w0 + (float)P1.y * w1) : 0.0f;
    oz = c ? ((float)P0.z * w0 + (float)P1.z * w1) : 0.0f;
}

// ---- fused: phases interleaved across the grid via stride permutation ----
// b' = (blockIdx.x * S) % TOT, gcd(S,TOT)==1 -> bijection. Mixes TA-heavy
// verts blocks with TA-light tets/uvs blocks on every CU so the VALU/store
// work of tets/uvs hides inside the verts gather stalls.
__global__ void __launch_bounds__(256) dmtet_fused_kernel(
        const float* __restrict__ pos,
        const float* __restrict__ sdf,
        const int* __restrict__ tet,
        const int* __restrict__ edges,
        const int* __restrict__ idx_map,
        const v4h* __restrict__ packed,        // may be null (fallback)
        float* __restrict__ verts,
        float* __restrict__ faces_out,
        float* __restrict__ uvidx_out,
        v4f* __restrict__ uvs,
        int Eu, int T, int Ngrid,
        int vBlocks, int tBlocks, int TOT, int S,
        float step, float pad) {
    int b = (int)(((long long)blockIdx.x * S) % TOT);

    if (b < vBlocks) {
        // ---------- vertex interpolation: 4 edges per thread ----------
        int t = b * blockDim.x + threadIdx.x;
        int e0 = 4 * t;
        if (e0 >= Eu) return;

        if (packed && e0 + 4 <= Eu) {
            v4i edA = __builtin_nontemporal_load((const v4i*)(edges + 2LL * e0));
            v4i edB = __builtin_nontemporal_load((const v4i*)(edges + 2LL * e0 + 4));
            // issue all 8 gathers up front (MLP)
            v4h P0 = packed[edA.x], P1 = packed[edA.y];
            v4h P2 = packed[edA.z], P3 = packed[edA.w];
            v4h P4 = packed[edB.x], P5 = packed[edB.y];
            v4h P6 = packed[edB.z], P7 = packed[edB.w];

            float x0,y0,z0,x1,y1,z1,x2,y2,z2,x3,y3,z3;
            interp_edge(P0, P1, x0, y0, z0);
            interp_edge(P2, P3, x1, y1, z1);
            interp_edge(P4, P5, x2, y2, z2);
            interp_edge(P6, P7, x3, y3, z3);

            v4f r0 = {x0, y0, z0, x1};
            v4f r1 = {y1, z1, x2, y2};
            v4f r2 = {z2, x3, y3, z3};
            v4f* o = (v4f*)(verts + 3LL * e0);
            o[0] = r0; o[1] = r1; o[2] = r2;
        } else {
            int eEnd = (e0 + 4 < Eu) ? e0 + 4 : Eu;
            for (int e = e0; e < eEnd; ++e) {
                v2i ed = *(const v2i*)(edges + 2LL * e);
                float ox, oy, oz;
                if (packed) {
                    interp_edge(packed[ed.x], packed[ed.y], ox, oy, oz);
                } else {
                    float s0 = sdf[ed.x], s1 = sdf[ed.y];
                    bool c = (s0 > 0.0f) != (s1 > 0.0f);
                    float d = c ? (s0 - s1) : 1.0f;
                    float w0 = -s1 / d, w1 = s0 / d;
                    const float* p0 = pos + 3LL * ed.x;
                    const float* p1 = pos + 3LL * ed.y;
                    ox = c ? (p0[0] * w0 + p1[0] * w1) : 0.0f;
                    oy = c ? (p0[1] * w0 + p1[1] * w1) : 0.0f;
                    oz = c ? (p0[2] * w0 + p1[2] * w1) : 0.0f;
                }
                verts[3LL * e + 0] = ox;
                verts[3LL * e + 1] = oy;
                verts[3LL * e + 2] = oz;
            }
        }
    } else if (b < vBlocks + tBlocks) {
        // ---------- per-tet faces + uv_idx ----------
        int t = (b - vBlocks) * blockDim.x + threadIdx.x;
        if (t >= T) return;

        v4i v  = __builtin_nontemporal_load((const v4i*)(tet + 4LL * t));
        v4i m0 = __builtin_nontemporal_load((const v4i*)(idx_map + 6LL * t));
        v2i m1 = __builtin_nontemporal_load((const v2i*)(idx_map + 6LL * t + 4));

        int idx = (sdf[v.x] > 0.0f ? 1 : 0) | (sdf[v.y] > 0.0f ? 2 : 0) |
                  (sdf[v.z] > 0.0f ? 4 : 0) | (sdf[v.w] > 0.0f ? 8 : 0);
        int row = c_tri_pack[idx];

        float f[6];
        #pragma unroll
        for (int j = 0; j < 6; ++j) {
            int tri3 = (row >> (3 * j)) & 7;        // tri+1, 0 = unused
            int cl = tri3 - 1;                       // valid only when tri3>0
            int pick = m0.x;
            pick = (cl == 1) ? m0.y : pick;
            pick = (cl == 2) ? m0.z : pick;
            pick = (cl == 3) ? m0.w : pick;
            pick = (cl == 4) ? m1.x : pick;
            pick = (cl == 5) ? m1.y : pick;
            f[j] = (tri3 != 0) ? (float)pick : -1.0f;
        }
        long long o = 6LL * t;
        {
            v2f s0 = {f[0], f[1]}, s1 = {f[2], f[3]}, s2 = {f[4], f[5]};
            v2f* fo = (v2f*)(faces_out + o);
            fo[0] = s0; fo[1] = s1; fo[2] = s2;
        }

        int base = 4 * t;   // tet_idx == t since T == Ngrid*Ngrid
        bool tv0 = (row & 7) != 0;          // ntri > 0 (and tet valid)
        bool tv1 = ((row >> 9) & 7) != 0;   // ntri > 1
        float u0 = tv0 ? (float)(base)     : -1.0f;
        float u1 = tv0 ? (float)(base + 1) : -1.0f;
        float u2 = tv0 ? (float)(base + 2) : -1.0f;
        float u3 = tv1 ? (float)(base)     : -1.0f;
        float u4 = tv1 ? (float)(base + 2) : -1.0f;
        float u5 = tv1 ? (float)(base + 3) : -1.0f;
        v2f s0 = {u0, u1}, s1 = {u2, u3}, s2 = {u4, u5};
        v2f* uo = (v2f*)(uvidx_out + o);
        uo[0] = s0; uo[1] = s1; uo[2] = s2;
    } else {
        // ---------- UV atlas: one float4 (two corners) per thread ----------
        int k = (b - vBlocks - tBlocks) * blockDim.x + threadIdx.x;
        int npairs = Ngrid * Ngrid * 2;
        if (k >= npairs) return;
        int q = k >> 1;
        int h = k & 1;
        int gx = q % Ngrid;
        int gy = q / Ngrid;
        float x = (float)gx * step;
        float y = (float)gy * step;
        v4f out;
        if (h == 0) { out.x = x;       out.y = y;       out.z = x + pad; out.w = y; }
        else        { out.x = x + pad; out.y = y + pad; out.z = x;       out.w = y + pad; }
        uvs[k] = out;
    }
}

static int gcd_i(int a, int b) { while (b) { int r = a % b; a = b; b = r; } return a; }

extern "C" void kernel_launch(void* const* d_in, const int* in_sizes, int n_in,
                              void* d_out, int out_size, void* d_ws, size_t ws_size,
                              hipStream_t stream) {
    const float* pos     = (const float*)d_in[0];
    const float* sdf     = (const float*)d_in[1];
    const int*   tet     = (const int*)d_in[2];
    const int*   edges   = (const int*)d_in[3];
    const int*   idx_map = (const int*)d_in[4];

    int Nv = in_sizes[0] / 3;
    int T  = in_sizes[2] / 4;
    int Eu = in_sizes[3] / 2;

    long long half = (2LL * T + 1) / 2;
    int Ngrid = (int)ceil(sqrt((double)half));
    while ((long long)Ngrid * Ngrid < half) Ngrid++;
    while ((long long)(Ngrid - 1) * (Ngrid - 1) >= half) Ngrid--;

    float* out   = (float*)d_out;
    float* verts = out;
    float* faces = verts + 3LL * Eu;
    float* uvs   = faces + 6LL * T;
    float* uvidx = uvs   + 8LL * Ngrid * Ngrid;

    float step = (float)((1.0 - 1.0 / (double)Ngrid) / (double)(Ngrid - 1));
    float pad  = 0.9f / (float)Ngrid;

    const int BLK = 256;
    bool usePacked = (ws_size >= (size_t)Nv * 8);
    v4h* packed = usePacked ? (v4h*)d_ws : nullptr;

    if (usePacked) {
        int pthreads = (Nv + 3) / 4;
        pack_kernel<<<(pthreads + BLK - 1) / BLK, BLK, 0, stream>>>(
            pos, sdf, packed, Nv);
    }

    int vthreads = (Eu + 3) / 4;
    int vBlocks = (vthreads + BLK - 1) / BLK;
    int tBlocks = (T + BLK - 1) / BLK;
    int npairs  = Ngrid * Ngrid * 2;
    int uBlocks = (npairs + BLK - 1) / BLK;
    int TOT = vBlocks + tBlocks + uBlocks;

    // stride permutation: golden-ratio-ish stride, coprime with TOT
    int S = (int)(0.618 * TOT);
    if (S < 1) S = 1;
    while (gcd_i(S, TOT) != 1) S++;

    dmtet_fused_kernel<<<TOT, BLK, 0, stream>>>(
        pos, sdf, tet, edges, idx_map, packed,
        verts, faces, uvidx, (v4f*)uvs,
        Eu, T, Ngrid, vBlocks, tBlocks, TOT, S, step, pad);
}

// Round 12
// 295.872 us; speedup vs baseline: 1.0538x; 1.0538x over previous
//
#include <hip/hip_runtime.h>
#include <math.h>

typedef int      v2i __attribute__((ext_vector_type(2)));
typedef int      v4i __attribute__((ext_vector_type(4)));
typedef float    v2f __attribute__((ext_vector_type(2)));
typedef float    v4f __attribute__((ext_vector_type(4)));
typedef _Float16 v4h __attribute__((ext_vector_type(4)));

// Packed marching-tets rows: entry j = (tri_table[idx][j]+1) << (3*j)  (3 bits,
// 0 means "-1 / unused"), plus num_tri << 18. Generated from TRI_TABLE.
__constant__ int c_tri_pack[16] = {
    0,      262346, 262413, 705770, 262548, 681571, 713834, 262557,
    262389, 617045, 649308, 262562, 608981, 262476, 262283, 0};

// ---- pack {pos.xyz, sdf} into half4 (8 B) per vertex (into d_ws) ----
// Gather working set: 600K * 8B = 4.8 MB -> ~L2-resident per XCD.
__global__ void __launch_bounds__(256) pack_kernel(
        const float* __restrict__ pos, const float* __restrict__ sdf,
        v4h* __restrict__ packed, int N) {
    int t = blockIdx.x * blockDim.x + threadIdx.x;
    int v0 = 4 * t;
    if (v0 >= N) return;

    // fp16 sign-preserving sdf: tiny positive must stay positive so the
    // crossing mask matches the f32 sign test used in the tets phase.
    auto h_sdf = [](float s) -> _Float16 {
        _Float16 h = (_Float16)s;
        if (s > 0.0f && !(h > (_Float16)0)) h = (_Float16)6.0e-8f;
        return h;
    };

    if (v0 + 4 <= N) {
        const v4f* pos4 = (const v4f*)pos;
        v4f p0 = pos4[3LL * t], p1 = pos4[3LL * t + 1], p2 = pos4[3LL * t + 2];
        v4f s  = ((const v4f*)sdf)[t];
        v4h h0 = {(_Float16)p0.x, (_Float16)p0.y, (_Float16)p0.z, h_sdf(s.x)};
        v4h h1 = {(_Float16)p0.w, (_Float16)p1.x, (_Float16)p1.y, h_sdf(s.y)};
        v4h h2 = {(_Float16)p1.z, (_Float16)p1.w, (_Float16)p2.x, h_sdf(s.z)};
        v4h h3 = {(_Float16)p2.y, (_Float16)p2.z, (_Float16)p2.w, h_sdf(s.w)};
        // combine pairs into 16B stores
        v4f o01, o23;
        ((v4h*)&o01)[0] = h0; ((v4h*)&o01)[1] = h1;
        ((v4h*)&o23)[0] = h2; ((v4h*)&o23)[1] = h3;
        v4f* dst = (v4f*)(packed + v0);
        dst[0] = o01; dst[1] = o23;
    } else {
        for (int v = v0; v < N; ++v) {
            v4h o = {(_Float16)pos[3LL * v], (_Float16)pos[3LL * v + 1],
                     (_Float16)pos[3LL * v + 2], h_sdf(sdf[v])};
            packed[v] = o;
        }
    }
}

__device__ __forceinline__ void interp_edge(v4h P0, v4h P1,
                                            float& ox, float& oy, float& oz) {
    float s0 = (float)P0.w, s1 = (float)P1.w;
    bool c = (s0 > 0.0f) != (s1 > 0.0f);
    float d = c ? (s0 - s1) : 1.0f;
    float w0 = -s1 / d, w1 = s0 / d;
    ox = c ? ((float)P0.x * w0 + (float)P1.x * w1) : 0.0f;
    oy = c ? ((float)P0.y * w0 + (float)P1.y * w1) : 0.0f;
    oz = c ? ((float)P0.z * w0 + (float)P1.z * w1) : 0.0f;
}

// ---- fused: Bresenham phase interleave, ORDER-PRESERVING per phase ----
// Slot i is a verts block iff floor((i+1)*vB/TOT) > floor(i*vB/TOT); verts
// indices stay monotonically increasing (sorted-edge gather locality kept),
// while tets/uvs blocks are spread uniformly between them so every CU mixes
// TA-heavy verts waves with TA-light tets/uvs waves.
__global__ void __launch_bounds__(256) dmtet_fused_kernel(
        const float* __restrict__ pos,
        const float* __restrict__ sdf,
        const int* __restrict__ tet,
        const int* __restrict__ edges,
        const int* __restrict__ idx_map,
        const v4h* __restrict__ packed,        // may be null (fallback)
        float* __restrict__ verts,
        float* __restrict__ faces_out,
        float* __restrict__ uvidx_out,
        v4f* __restrict__ uvs,
        int Eu, int T, int Ngrid,
        int vBlocks, int tBlocks, int TOT,
        float step, float pad) {
    int i = blockIdx.x;
    long long vb = (long long)i * vBlocks;
    int vprev = (int)(vb / TOT);
    int vnext = (int)((vb + vBlocks) / TOT);
    int b = (vnext > vprev) ? vprev                    // verts block, in order
                            : vBlocks + (i - vprev);   // tets/uvs block, in order

    if (b < vBlocks) {
        // ---------- vertex interpolation: 4 edges per thread ----------
        int t = b * blockDim.x + threadIdx.x;
        int e0 = 4 * t;
        if (e0 >= Eu) return;

        if (packed && e0 + 4 <= Eu) {
            v4i edA = __builtin_nontemporal_load((const v4i*)(edges + 2LL * e0));
            v4i edB = __builtin_nontemporal_load((const v4i*)(edges + 2LL * e0 + 4));
            // issue all 8 gathers up front (MLP)
            v4h P0 = packed[edA.x], P1 = packed[edA.y];
            v4h P2 = packed[edA.z], P3 = packed[edA.w];
            v4h P4 = packed[edB.x], P5 = packed[edB.y];
            v4h P6 = packed[edB.z], P7 = packed[edB.w];

            float x0,y0,z0,x1,y1,z1,x2,y2,z2,x3,y3,z3;
            interp_edge(P0, P1, x0, y0, z0);
            interp_edge(P2, P3, x1, y1, z1);
            interp_edge(P4, P5, x2, y2, z2);
            interp_edge(P6, P7, x3, y3, z3);

            v4f r0 = {x0, y0, z0, x1};
            v4f r1 = {y1, z1, x2, y2};
            v4f r2 = {z2, x3, y3, z3};
            v4f* o = (v4f*)(verts + 3LL * e0);
            o[0] = r0; o[1] = r1; o[2] = r2;
        } else {
            int eEnd = (e0 + 4 < Eu) ? e0 + 4 : Eu;
            for (int e = e0; e < eEnd; ++e) {
                v2i ed = *(const v2i*)(edges + 2LL * e);
                float ox, oy, oz;
                if (packed) {
                    interp_edge(packed[ed.x], packed[ed.y], ox, oy, oz);
                } else {
                    float s0 = sdf[ed.x], s1 = sdf[ed.y];
                    bool c = (s0 > 0.0f) != (s1 > 0.0f);
                    float d = c ? (s0 - s1) : 1.0f;
                    float w0 = -s1 / d, w1 = s0 / d;
                    const float* p0 = pos + 3LL * ed.x;
                    const float* p1 = pos + 3LL * ed.y;
                    ox = c ? (p0[0] * w0 + p1[0] * w1) : 0.0f;
                    oy = c ? (p0[1] * w0 + p1[1] * w1) : 0.0f;
                    oz = c ? (p0[2] * w0 + p1[2] * w1) : 0.0f;
                }
                verts[3LL * e + 0] = ox;
                verts[3LL * e + 1] = oy;
                verts[3LL * e + 2] = oz;
            }
        }
    } else if (b < vBlocks + tBlocks) {
        // ---------- per-tet faces + uv_idx ----------
        int t = (b - vBlocks) * blockDim.x + threadIdx.x;
        if (t >= T) return;

        v4i v  = __builtin_nontemporal_load((const v4i*)(tet + 4LL * t));
        v4i m0 = __builtin_nontemporal_load((const v4i*)(idx_map + 6LL * t));
        v2i m1 = __builtin_nontemporal_load((const v2i*)(idx_map + 6LL * t + 4));

        int idx = (sdf[v.x] > 0.0f ? 1 : 0) | (sdf[v.y] > 0.0f ? 2 : 0) |
                  (sdf[v.z] > 0.0f ? 4 : 0) | (sdf[v.w] > 0.0f ? 8 : 0);
        int row = c_tri_pack[idx];

        float f[6];
        #pragma unroll
        for (int j = 0; j < 6; ++j) {
            int tri3 = (row >> (3 * j)) & 7;        // tri+1, 0 = unused
            int cl = tri3 - 1;                       // valid only when tri3>0
            int pick = m0.x;
            pick = (cl == 1) ? m0.y : pick;
            pick = (cl == 2) ? m0.z : pick;
            pick = (cl == 3) ? m0.w : pick;
            pick = (cl == 4) ? m1.x : pick;
            pick = (cl == 5) ? m1.y : pick;
            f[j] = (tri3 != 0) ? (float)pick : -1.0f;
        }
        long long o = 6LL * t;
        {
            v2f s0 = {f[0], f[1]}, s1 = {f[2], f[3]}, s2 = {f[4], f[5]};
            v2f* fo = (v2f*)(faces_out + o);
            fo[0] = s0; fo[1] = s1; fo[2] = s2;
        }

        int base = 4 * t;   // tet_idx == t since T == Ngrid*Ngrid
        bool tv0 = (row & 7) != 0;          // ntri > 0 (and tet valid)
        bool tv1 = ((row >> 9) & 7) != 0;   // ntri > 1
        float u0 = tv0 ? (float)(base)     : -1.0f;
        float u1 = tv0 ? (float)(base + 1) : -1.0f;
        float u2 = tv0 ? (float)(base + 2) : -1.0f;
        float u3 = tv1 ? (float)(base)     : -1.0f;
        float u4 = tv1 ? (float)(base + 2) : -1.0f;
        float u5 = tv1 ? (float)(base + 3) : -1.0f;
        v2f s0 = {u0, u1}, s1 = {u2, u3}, s2 = {u4, u5};
        v2f* uo = (v2f*)(uvidx_out + o);
        uo[0] = s0; uo[1] = s1; uo[2] = s2;
    } else {
        // ---------- UV atlas: one float4 (two corners) per thread ----------
        int k = (b - vBlocks - tBlocks) * blockDim.x + threadIdx.x;
        int npairs = Ngrid * Ngrid * 2;
        if (k >= npairs) return;
        int q = k >> 1;
        int h = k & 1;
        int gx = q % Ngrid;
        int gy = q / Ngrid;
        float x = (float)gx * step;
        float y = (float)gy * step;
        v4f out;
        if (h == 0) { out.x = x;       out.y = y;       out.z = x + pad; out.w = y; }
        else        { out.x = x + pad; out.y = y + pad; out.z = x;       out.w = y + pad; }
        uvs[k] = out;
    }
}

extern "C" void kernel_launch(void* const* d_in, const int* in_sizes, int n_in,
                              void* d_out, int out_size, void* d_ws, size_t ws_size,
                              hipStream_t stream) {
    const float* pos     = (const float*)d_in[0];
    const float* sdf     = (const float*)d_in[1];
    const int*   tet     = (const int*)d_in[2];
    const int*   edges   = (const int*)d_in[3];
    const int*   idx_map = (const int*)d_in[4];

    int Nv = in_sizes[0] / 3;
    int T  = in_sizes[2] / 4;
    int Eu = in_sizes[3] / 2;

    long long half = (2LL * T + 1) / 2;
    int Ngrid = (int)ceil(sqrt((double)half));
    while ((long long)Ngrid * Ngrid < half) Ngrid++;
    while ((long long)(Ngrid - 1) * (Ngrid - 1) >= half) Ngrid--;

    float* out   = (float*)d_out;
    float* verts = out;
    float* faces = verts + 3LL * Eu;
    float* uvs   = faces + 6LL * T;
    float* uvidx = uvs   + 8LL * Ngrid * Ngrid;

    float step = (float)((1.0 - 1.0 / (double)Ngrid) / (double)(Ngrid - 1));
    float pad  = 0.9f / (float)Ngrid;

    const int BLK = 256;
    bool usePacked = (ws_size >= (size_t)Nv * 8);
    v4h* packed = usePacked ? (v4h*)d_ws : nullptr;

    if (usePacked) {
        int pthreads = (Nv + 3) / 4;
        pack_kernel<<<(pthreads + BLK - 1) / BLK, BLK, 0, stream>>>(
            pos, sdf, packed, Nv);
    }

    int vthreads = (Eu + 3) / 4;
    int vBlocks = (vthreads + BLK - 1) / BLK;
    int tBlocks = (T + BLK - 1) / BLK;
    int npairs  = Ngrid * Ngrid * 2;
    int uBlocks = (npairs + BLK - 1) / BLK;
    int TOT = vBlocks + tBlocks + uBlocks;

    dmtet_fused_kernel<<<TOT, BLK, 0, stream>>>(
        pos, sdf, tet, edges, idx_map, packed,
        verts, faces, uvidx, (v4f*)uvs,
        Eu, T, Ngrid, vBlocks, tBlocks, TOT, step, pad);
}

// Round 13
// 291.196 us; speedup vs baseline: 1.0707x; 1.0161x over previous
//
#include <hip/hip_runtime.h>
#include <math.h>

typedef int      v2i __attribute__((ext_vector_type(2)));
typedef int      v4i __attribute__((ext_vector_type(4)));
typedef float    v2f __attribute__((ext_vector_type(2)));
typedef float    v4f __attribute__((ext_vector_type(4)));
typedef _Float16 v4h __attribute__((ext_vector_type(4)));

#define V0CAP 2048   // staged v0-range capacity (16 KB LDS)

// Packed marching-tets rows: entry j = (tri_table[idx][j]+1) << (3*j)  (3 bits,
// 0 means "-1 / unused"), plus num_tri << 18. Generated from TRI_TABLE.
__constant__ int c_tri_pack[16] = {
    0,      262346, 262413, 705770, 262548, 681571, 713834, 262557,
    262389, 617045, 649308, 262562, 608981, 262476, 262283, 0};

// ---- pack {pos.xyz, sdf} into half4 (8 B) per vertex (into d_ws) ----
__global__ void __launch_bounds__(256) pack_kernel(
        const float* __restrict__ pos, const float* __restrict__ sdf,
        v4h* __restrict__ packed, int N) {
    int t = blockIdx.x * blockDim.x + threadIdx.x;
    int v0 = 4 * t;
    if (v0 >= N) return;

    // fp16 sign-preserving sdf: tiny positive must stay positive so the
    // crossing mask matches the f32 sign test used in the tets phase.
    auto h_sdf = [](float s) -> _Float16 {
        _Float16 h = (_Float16)s;
        if (s > 0.0f && !(h > (_Float16)0)) h = (_Float16)6.0e-8f;
        return h;
    };

    if (v0 + 4 <= N) {
        const v4f* pos4 = (const v4f*)pos;
        v4f p0 = pos4[3LL * t], p1 = pos4[3LL * t + 1], p2 = pos4[3LL * t + 2];
        v4f s  = ((const v4f*)sdf)[t];
        v4h h0 = {(_Float16)p0.x, (_Float16)p0.y, (_Float16)p0.z, h_sdf(s.x)};
        v4h h1 = {(_Float16)p0.w, (_Float16)p1.x, (_Float16)p1.y, h_sdf(s.y)};
        v4h h2 = {(_Float16)p1.z, (_Float16)p1.w, (_Float16)p2.x, h_sdf(s.z)};
        v4h h3 = {(_Float16)p2.y, (_Float16)p2.z, (_Float16)p2.w, h_sdf(s.w)};
        v4f o01, o23;
        ((v4h*)&o01)[0] = h0; ((v4h*)&o01)[1] = h1;
        ((v4h*)&o23)[0] = h2; ((v4h*)&o23)[1] = h3;
        v4f* dst = (v4f*)(packed + v0);
        dst[0] = o01; dst[1] = o23;
    } else {
        for (int v = v0; v < N; ++v) {
            v4h o = {(_Float16)pos[3LL * v], (_Float16)pos[3LL * v + 1],
                     (_Float16)pos[3LL * v + 2], h_sdf(sdf[v])};
            packed[v] = o;
        }
    }
}

__device__ __forceinline__ void interp_edge(v4h P0, v4h P1,
                                            float& ox, float& oy, float& oz) {
    float s0 = (float)P0.w, s1 = (float)P1.w;
    bool c = (s0 > 0.0f) != (s1 > 0.0f);
    float d = c ? (s0 - s1) : 1.0f;
    float w0 = -s1 / d, w1 = s0 / d;
    ox = c ? ((float)P0.x * w0 + (float)P1.x * w1) : 0.0f;
    oy = c ? ((float)P0.y * w0 + (float)P1.y * w1) : 0.0f;
    oz = c ? ((float)P0.z * w0 + (float)P1.z * w1) : 0.0f;
}

// ---- fused, sequential phases: [verts | tets | uvs] ----
// Verts: edges are lexicographically sorted, so a 1024-edge block's v0
// endpoints span a small contiguous vertex range (mean ~170). Stage that
// range into LDS (coalesced) so the v0 gather costs zero TA lanes; only
// the v1 gather stays divergent -> halves divergent global lanes.
__global__ void __launch_bounds__(256) dmtet_fused_kernel(
        const float* __restrict__ pos,
        const float* __restrict__ sdf,
        const int* __restrict__ tet,
        const int* __restrict__ edges,
        const int* __restrict__ idx_map,
        const v4h* __restrict__ packed,        // may be null (fallback)
        float* __restrict__ verts,
        float* __restrict__ faces_out,
        float* __restrict__ uvidx_out,
        v4f* __restrict__ uvs,
        int Eu, int T, int Ngrid,
        int vBlocks, int tBlocks,
        float step, float pad) {
    __shared__ v4h sh[V0CAP];
    int b = blockIdx.x;

    if (b < vBlocks) {
        // ---------- vertex interpolation: 4 edges per thread ----------
        int firstE = b * 1024;
        int lastE  = firstE + 1023 < Eu - 1 ? firstE + 1023 : Eu - 1;
        int v0min = 0, range = V0CAP + 1;
        if (packed) {
            v0min = edges[2LL * firstE];
            int v0max = edges[2LL * lastE];
            range = v0max - v0min + 1;
        }
        bool useLds = packed && (range <= V0CAP);
        if (useLds) {
            for (int v = threadIdx.x; v < range; v += 256)
                sh[v] = packed[v0min + v];
        }
        __syncthreads();

        int e0 = firstE + 4 * threadIdx.x;
        if (e0 >= Eu) return;

        if (packed && e0 + 4 <= Eu) {
            v4i edA = __builtin_nontemporal_load((const v4i*)(edges + 2LL * e0));
            v4i edB = __builtin_nontemporal_load((const v4i*)(edges + 2LL * e0 + 4));
            // v1 gathers (divergent) issued up front for MLP
            v4h P1 = packed[edA.y];
            v4h P3 = packed[edA.w];
            v4h P5 = packed[edB.y];
            v4h P7 = packed[edB.w];
            // v0 reads: LDS (or global fallback)
            v4h P0 = useLds ? sh[edA.x - v0min] : packed[edA.x];
            v4h P2 = useLds ? sh[edA.z - v0min] : packed[edA.z];
            v4h P4 = useLds ? sh[edB.x - v0min] : packed[edB.x];
            v4h P6 = useLds ? sh[edB.z - v0min] : packed[edB.z];

            float x0,y0,z0,x1,y1,z1,x2,y2,z2,x3,y3,z3;
            interp_edge(P0, P1, x0, y0, z0);
            interp_edge(P2, P3, x1, y1, z1);
            interp_edge(P4, P5, x2, y2, z2);
            interp_edge(P6, P7, x3, y3, z3);

            v4f r0 = {x0, y0, z0, x1};
            v4f r1 = {y1, z1, x2, y2};
            v4f r2 = {z2, x3, y3, z3};
            v4f* o = (v4f*)(verts + 3LL * e0);
            o[0] = r0; o[1] = r1; o[2] = r2;
        } else {
            int eEnd = (e0 + 4 < Eu) ? e0 + 4 : Eu;
            for (int e = e0; e < eEnd; ++e) {
                v2i ed = *(const v2i*)(edges + 2LL * e);
                float ox, oy, oz;
                if (packed) {
                    v4h P0 = useLds ? sh[ed.x - v0min] : packed[ed.x];
                    interp_edge(P0, packed[ed.y], ox, oy, oz);
                } else {
                    float s0 = sdf[ed.x], s1 = sdf[ed.y];
                    bool c = (s0 > 0.0f) != (s1 > 0.0f);
                    float d = c ? (s0 - s1) : 1.0f;
                    float w0 = -s1 / d, w1 = s0 / d;
                    const float* p0 = pos + 3LL * ed.x;
                    const float* p1 = pos + 3LL * ed.y;
                    ox = c ? (p0[0] * w0 + p1[0] * w1) : 0.0f;
                    oy = c ? (p0[1] * w0 + p1[1] * w1) : 0.0f;
                    oz = c ? (p0[2] * w0 + p1[2] * w1) : 0.0f;
                }
                verts[3LL * e + 0] = ox;
                verts[3LL * e + 1] = oy;
                verts[3LL * e + 2] = oz;
            }
        }
    } else if (b < vBlocks + tBlocks) {
        // ---------- per-tet faces + uv_idx ----------
        int t = (b - vBlocks) * blockDim.x + threadIdx.x;
        if (t >= T) return;

        v4i v  = __builtin_nontemporal_load((const v4i*)(tet + 4LL * t));
        v4i m0 = __builtin_nontemporal_load((const v4i*)(idx_map + 6LL * t));
        v2i m1 = __builtin_nontemporal_load((const v2i*)(idx_map + 6LL * t + 4));

        int idx = (sdf[v.x] > 0.0f ? 1 : 0) | (sdf[v.y] > 0.0f ? 2 : 0) |
                  (sdf[v.z] > 0.0f ? 4 : 0) | (sdf[v.w] > 0.0f ? 8 : 0);
        int row = c_tri_pack[idx];

        float f[6];
        #pragma unroll
        for (int j = 0; j < 6; ++j) {
            int tri3 = (row >> (3 * j)) & 7;        // tri+1, 0 = unused
            int cl = tri3 - 1;                       // valid only when tri3>0
            int pick = m0.x;
            pick = (cl == 1) ? m0.y : pick;
            pick = (cl == 2) ? m0.z : pick;
            pick = (cl == 3) ? m0.w : pick;
            pick = (cl == 4) ? m1.x : pick;
            pick = (cl == 5) ? m1.y : pick;
            f[j] = (tri3 != 0) ? (float)pick : -1.0f;
        }
        long long o = 6LL * t;
        {
            v2f s0 = {f[0], f[1]}, s1 = {f[2], f[3]}, s2 = {f[4], f[5]};
            v2f* fo = (v2f*)(faces_out + o);
            fo[0] = s0; fo[1] = s1; fo[2] = s2;
        }

        int base = 4 * t;   // tet_idx == t since T == Ngrid*Ngrid
        bool tv0 = (row & 7) != 0;          // ntri > 0 (and tet valid)
        bool tv1 = ((row >> 9) & 7) != 0;   // ntri > 1
        float u0 = tv0 ? (float)(base)     : -1.0f;
        float u1 = tv0 ? (float)(base + 1) : -1.0f;
        float u2 = tv0 ? (float)(base + 2) : -1.0f;
        float u3 = tv1 ? (float)(base)     : -1.0f;
        float u4 = tv1 ? (float)(base + 2) : -1.0f;
        float u5 = tv1 ? (float)(base + 3) : -1.0f;
        v2f s0 = {u0, u1}, s1 = {u2, u3}, s2 = {u4, u5};
        v2f* uo = (v2f*)(uvidx_out + o);
        uo[0] = s0; uo[1] = s1; uo[2] = s2;
    } else {
        // ---------- UV atlas: one float4 (two corners) per thread ----------
        int k = (b - vBlocks - tBlocks) * blockDim.x + threadIdx.x;
        int npairs = Ngrid * Ngrid * 2;
        if (k >= npairs) return;
        int q = k >> 1;
        int h = k & 1;
        int gx = q % Ngrid;
        int gy = q / Ngrid;
        float x = (float)gx * step;
        float y = (float)gy * step;
        v4f out;
        if (h == 0) { out.x = x;       out.y = y;       out.z = x + pad; out.w = y; }
        else        { out.x = x + pad; out.y = y + pad; out.z = x;       out.w = y + pad; }
        uvs[k] = out;
    }
}

extern "C" void kernel_launch(void* const* d_in, const int* in_sizes, int n_in,
                              void* d_out, int out_size, void* d_ws, size_t ws_size,
                              hipStream_t stream) {
    const float* pos     = (const float*)d_in[0];
    const float* sdf     = (const float*)d_in[1];
    const int*   tet     = (const int*)d_in[2];
    const int*   edges   = (const int*)d_in[3];
    const int*   idx_map = (const int*)d_in[4];

    int Nv = in_sizes[0] / 3;
    int T  = in_sizes[2] / 4;
    int Eu = in_sizes[3] / 2;

    long long half = (2LL * T + 1) / 2;
    int Ngrid = (int)ceil(sqrt((double)half));
    while ((long long)Ngrid * Ngrid < half) Ngrid++;
    while ((long long)(Ngrid - 1) * (Ngrid - 1) >= half) Ngrid--;

    float* out   = (float*)d_out;
    float* verts = out;
    float* faces = verts + 3LL * Eu;
    float* uvs   = faces + 6LL * T;
    float* uvidx = uvs   + 8LL * Ngrid * Ngrid;

    float step = (float)((1.0 - 1.0 / (double)Ngrid) / (double)(Ngrid - 1));
    float pad  = 0.9f / (float)Ngrid;

    const int BLK = 256;
    bool usePacked = (ws_size >= (size_t)Nv * 8);
    v4h* packed = usePacked ? (v4h*)d_ws : nullptr;

    if (usePacked) {
        int pthreads = (Nv + 3) / 4;
        pack_kernel<<<(pthreads + BLK - 1) / BLK, BLK, 0, stream>>>(
            pos, sdf, packed, Nv);
    }

    int vBlocks = (Eu + 1023) / 1024;
    int tBlocks = (T + BLK - 1) / BLK;
    int npairs  = Ngrid * Ngrid * 2;
    int uBlocks = (npairs + BLK - 1) / BLK;

    dmtet_fused_kernel<<<vBlocks + tBlocks + uBlocks, BLK, 0, stream>>>(
        pos, sdf, tet, edges, idx_map, packed,
        verts, faces, uvidx, (v4f*)uvs,
        Eu, T, Ngrid, vBlocks, tBlocks, step, pad);
}